// Round 2
// baseline (232.774 us; speedup 1.0000x reference)
//
#include <hip/hip_runtime.h>

// VectorQuantizer: z [8,64,64,64] fp32 (BCHW), embedding [8192,64] fp32.
// Outputs (concat): z_q [8,64,64,64] fp32 (BCHW), indices [32768] as fp32.
//
// R15: single-product fp16 scoring (was 3-product bf16 hi/lo).
// R14 post-mortem: VALUBusy includes MFMA cycles on gfx950 fallback formula;
// real VALU ~25%, matrix ~38% -> matrix work is the largest component.
// fp16 rounding error on unit vectors: |a-fp16(a)| ~ 2.8e-4; per-code score
// error DIFFERENCE sigma ~ 7e-5. MARGIN 6e-4 (~8 sigma) flags every pixel
// whose argmax could flip; k_recheck resolves those in exact fp32. Cuts MFMA
// count 3x (6 -> 2 per K-64 chain), LDS reads 2x, staging/FETCH 2x, LDS 16KB.
// Selection (R14, kept): v = dot + 2 - 0.5|e|^2 > 0, 6-bit candidate id
// stuffed in low mantissa bits (v_and_or_b32), top-2 via med3+max (3 ops/elem).
// Staging (R12, proven): global_load_lds 16B registerless from pre-swizzled
// codebook, LDS double-buffer, 1 barrier/stage, 0 bank conflicts.

#define NPIX 32768
#define NE   8192
#define EDIM 64
#define HW   4096
#define NSTAGE 64           // codes per LDS stage (4 subtiles of 16)
#define KSPLIT 8
#define CPS  (NE / KSPLIT)  // 1024 codes per split
#define NSTG (CPS / NSTAGE) // 16 stages per block
#define MARGIN 6.0e-4f

typedef _Float16 f16x8 __attribute__((ext_vector_type(8)));
typedef float f32x4  __attribute__((ext_vector_type(4)));

__device__ __forceinline__ short f2h_bits(float x) {
    _Float16 h = (_Float16)x;
    short s; __builtin_memcpy(&s, &h, 2); return s;
}
// map float to unsigned with same total order
__device__ __forceinline__ unsigned int order_u32(float f) {
    unsigned int s = __float_as_uint(f);
    return (s & 0x80000000u) ? ~s : (s | 0x80000000u);
}
// async global->LDS, 16B/lane; HW writes lane i at lds_base + i*16 (wave-uniform base)
__device__ __forceinline__ void gload_lds16(const void* g, void* l) {
    __builtin_amdgcn_global_load_lds(
        (const __attribute__((address_space(1))) void*)g,
        (__attribute__((address_space(3))) void*)l, 16, 0, 0);
}

// ---------------- prep (fused): codebook (swizzled fp16) + pixels ------------
// esw layout = exactly the k_mfma LDS stage image: per 64-code stage, 8 combos
// (sub[4] x {k0,k1}) x 1KB; within combo, MFMA-B fragment order: slot
// frag_lane = (o&3)*16 + code_col holds 8 channels (16B).
__global__ __launch_bounds__(256) void k_prep(const float* __restrict__ emb,
                                              const float* __restrict__ z,
                                              float* __restrict__ e_norm,
                                              float* __restrict__ se_half,
                                              short* __restrict__ esw,
                                              float* __restrict__ zn,
                                              unsigned* __restrict__ counter) {
    if (blockIdx.x == 0 && threadIdx.x == 0) *counter = 0u;
    if (blockIdx.x < NE / 4) {
        // --- codebook: 1 code per wave, lane = channel ---
        const int wave = threadIdx.x >> 6;
        const int lane = threadIdx.x & 63;
        const int n = blockIdx.x * 4 + wave;
        float v = emb[n * EDIM + lane];
        float ss = v * v;
        #pragma unroll
        for (int off = 32; off; off >>= 1) ss += __shfl_xor(ss, off, 64);
        const float inv = 1.0f / fmaxf(sqrtf(ss), 1e-12f);
        const float en = v * inv;
        e_norm[n * EDIM + lane] = en;
        // swizzled fp16 write (c = lane)
        const int stage = n >> 6, cs = n & 63;
        const int sub = cs >> 4, colb = cs & 15;
        const int o = lane >> 3, j = lane & 7;     // o: khalf=o>>2, quad=o&3
        const int slot = ((o & 3) * 16 + colb) * 8 + j;
        short* sbase = esw + stage * 4096 + (sub * 2 + (o >> 2)) * 512;
        sbase[slot] = f2h_bits(en);
        float s2 = en * en;
        #pragma unroll
        for (int off = 32; off; off >>= 1) s2 += __shfl_xor(s2, off, 64);
        if (lane == 0) se_half[n] = 0.5f * s2;
    } else {
        // --- pixels: normalize -> zn fp32 row-major [p][c] ---
        const int p = (blockIdx.x - NE / 4) * 256 + threadIdx.x;
        const int b = p >> 12, hw = p & (HW - 1);
        const float* zp = z + b * (EDIM * HW) + hw;
        float ss = 0.0f;
        for (int c = 0; c < EDIM; ++c) { const float v = zp[c * HW]; ss = fmaf(v, v, ss); }
        const float inv = 1.0f / fmaxf(sqrtf(ss), 1e-12f);
        for (int c4 = 0; c4 < 16; ++c4) {
            float4 o;
            o.x = zp[(c4 * 4 + 0) * HW] * inv;
            o.y = zp[(c4 * 4 + 1) * HW] * inv;
            o.z = zp[(c4 * 4 + 2) * HW] * inv;
            o.w = zp[(c4 * 4 + 3) * HW] * inv;
            *(float4*)(zn + p * EDIM + c4 * 4) = o;
        }
    }
}

// ---------------- k_mfma: split-K partial top-2 per pixel (max-space) --------
// Block: 4 waves x 32 pixels = 128 pixels, one codebook eighth (blockIdx.y).
// v = acc[r] = dot - 0.5|e|^2 + 2 > 0; argmin dist == argmax v. Low 6 mantissa
// bits carry the candidate id (stage*4+sub); near-ties (< MARGIN, covers fp16
// rounding at ~8 sigma) are flagged and resolved exactly in k_recheck.
// Layouts (HW-verified): A[m=lane&15][k=quad*8+j], B[k=quad*8+j][n=lane&15],
// C/D row=(lane>>4)*4+reg, col=lane&15.
__global__ __launch_bounds__(256, 1) void k_mfma(const float* __restrict__ zn,
                                                 const short* __restrict__ esw,
                                                 const float* __restrict__ se_half,
                                                 float2* __restrict__ pv,   // [g][p] {b1,b2} (max-space)
                                                 unsigned* __restrict__ pi) // [g][p] i1
{
    __shared__ __align__(16) short es[2][NSTAGE * EDIM];   // 2 x 8KB

    const int tid  = threadIdx.x;             // 0..255
    const int wave = tid >> 6, lane = tid & 63;
    const int quad = lane >> 4, col = lane & 15;
    const int p0   = blockIdx.x * 128 + wave * 32;  // wave's 32 pixels (2 sets)
    const int g    = blockIdx.y;                    // codebook eighth
    const int kbase = g * CPS;

    // A fragments: 2 sets of 16 pixels; fp32 zn -> fp16 (single product)
    f16x8 ah[2][2];
    #pragma unroll
    for (int s = 0; s < 2; ++s) {
        const float* zr = zn + (p0 + s * 16 + col) * EDIM;
        #pragma unroll
        for (int kc = 0; kc < 2; ++kc) {
            float f[8];
            *(float4*)(f + 0) = *(const float4*)(zr + kc * 32 + quad * 8 + 0);
            *(float4*)(f + 4) = *(const float4*)(zr + kc * 32 + quad * 8 + 4);
            #pragma unroll
            for (int i = 0; i < 8; ++i) ah[s][kc][i] = (_Float16)f[i];
        }
    }

    // top-2 state in max-space; values stuffed with 6-bit id; b1 >= b2 invariant
    float b1[2][4], b2[2][4];
    #pragma unroll
    for (int s = 0; s < 2; ++s)
        #pragma unroll
        for (int r = 0; r < 4; ++r) { b1[s][r] = 0.0f; b2[s][r] = 0.0f; }

    // this wave's staging window: src and dst are both uniform + lane*16
    const int combo0 = wave * 2;
    const char* gsrc0 = (const char*)esw + (size_t)kbase * 128
                        + combo0 * 1024 + lane * 16;
    // prologue: issue stage 0 -> buf 0
    #pragma unroll
    for (int it = 0; it < 2; ++it)
        gload_lds16(gsrc0 + it * 1024, (char*)&es[0][0] + (combo0 + it) * 1024);

    for (int nb = 0; nb < NSTG; ++nb) {
        const int cur = nb & 1;
        const int n0 = kbase + nb * NSTAGE;
        __syncthreads();   // vmcnt drained: buf[cur] complete; buf[cur^1] reusable
        if (nb + 1 < NSTG) {
            const char* gsrc = gsrc0 + (size_t)(nb + 1) * (NSTAGE * EDIM * 2);
            #pragma unroll
            for (int it = 0; it < 2; ++it)
                gload_lds16(gsrc + it * 1024,
                            (char*)&es[cur ^ 1][0] + (combo0 + it) * 1024);
        }
        // per-stage bias prefetch (L1/L2-resident, hidden under MFMA)
        float nse[4];
        #pragma unroll
        for (int sub = 0; sub < 4; ++sub) nse[sub] = 2.0f - se_half[n0 + sub * 16 + col];

        const short* esb = es[cur];
        #pragma unroll
        for (int sub = 0; sub < 4; ++sub) {
            const short* base = esb + sub * 1024;
            const f16x8 bh0 = *(const f16x8*)(base + lane * 8);
            const f16x8 bh1 = *(const f16x8*)(base + 512 + lane * 8);
            const float m = nse[sub];
            const f32x4 cini = {m, m, m, m};
            const unsigned sid = (unsigned)((nb << 2) | sub);  // 6-bit id, uniform
            #pragma unroll
            for (int s = 0; s < 2; ++s) {
                // 2-deep chain seeded with C = {2 - 0.5|e|^2}
                f32x4 acc;
                acc = __builtin_amdgcn_mfma_f32_16x16x32_f16(ah[s][0], bh0, cini, 0, 0, 0);
                acc = __builtin_amdgcn_mfma_f32_16x16x32_f16(ah[s][1], bh1, acc, 0, 0, 0);
                #pragma unroll
                for (int r = 0; r < 4; ++r) {
                    // stuff candidate id into low mantissa bits (v_and_or_b32)
                    const float v = __uint_as_float(
                        (__float_as_uint(acc[r]) & 0xFFFFFFC0u) | sid);
                    // b1>=b2 invariant -> med3 == new 2nd-max; then running max
                    b2[s][r] = __builtin_amdgcn_fmed3f(v, b2[s][r], b1[s][r]);
                    b1[s][r] = fmaxf(b1[s][r], v);
                }
            }
        }
    }

    // recover winning index from b1's stuffed id (col is lane-implicit)
    int i1[2][4];
    #pragma unroll
    for (int s = 0; s < 2; ++s)
        #pragma unroll
        for (int r = 0; r < 4; ++r) {
            const unsigned id6 = __float_as_uint(b1[s][r]) & 63u;
            i1[s][r] = kbase + (int)(id6 << 4) + col;
        }

    // merge top-2 across the 16 col-lanes (xor 1,2,4,8 stays inside quad group)
    #pragma unroll
    for (int m = 1; m <= 8; m <<= 1) {
        #pragma unroll
        for (int s = 0; s < 2; ++s)
            #pragma unroll
            for (int r = 0; r < 4; ++r) {
                const float ob1 = __shfl_xor(b1[s][r], m, 64);
                const int   oi1 = __shfl_xor(i1[s][r], m, 64);
                const float ob2 = __shfl_xor(b2[s][r], m, 64);
                const bool take = (ob1 > b1[s][r]) || (ob1 == b1[s][r] && oi1 < i1[s][r]);
                b2[s][r] = fmaxf(fmaxf(b2[s][r], ob2), fminf(b1[s][r], ob1));
                b1[s][r] = take ? ob1 : b1[s][r];
                i1[s][r] = take ? oi1 : i1[s][r];
            }
    }
    if (col == 0) {
        #pragma unroll
        for (int s = 0; s < 2; ++s)
            #pragma unroll
            for (int r = 0; r < 4; ++r) {
                const int p = p0 + s * 16 + quad * 4 + r;   // C/D row = quad*4 + r
                pv[g * NPIX + p] = make_float2(b1[s][r], b2[s][r]);
                pi[g * NPIX + p] = (unsigned)i1[s][r];
            }
    }
}

// ---------------- merge: combine KSPLIT partials (max-space), flag -----------
__global__ __launch_bounds__(256) void k_merge(const float2* __restrict__ pv,
                                               const unsigned* __restrict__ pi,
                                               unsigned* __restrict__ idx_arr,
                                               unsigned* __restrict__ list,
                                               unsigned* __restrict__ counter,
                                               unsigned long long* __restrict__ packed) {
    const int p = blockIdx.x * 256 + threadIdx.x;
    float2 v[KSPLIT]; unsigned ix[KSPLIT];
    #pragma unroll
    for (int gg = 0; gg < KSPLIT; ++gg) { v[gg] = pv[gg * NPIX + p]; ix[gg] = pi[gg * NPIX + p]; }
    // ascending group order + strict > == np first-occurrence tie semantics
    float b1 = v[0].x; unsigned i1 = ix[0]; int win = 0;
    #pragma unroll
    for (int gg = 1; gg < KSPLIT; ++gg)
        if (v[gg].x > b1) { b1 = v[gg].x; i1 = ix[gg]; win = gg; }
    float b2 = -3.0e38f;
    #pragma unroll
    for (int gg = 0; gg < KSPLIT; ++gg) {
        b2 = fmaxf(b2, v[gg].y);
        if (gg != win) b2 = fmaxf(b2, v[gg].x);
    }
    const bool fl = (b1 - b2 < MARGIN);   // gap in v-space == gap in dist/2
    idx_arr[p] = i1 | (fl ? 0x80000000u : 0u);
    if (fl) {
        packed[p] = ~0ull;
        const unsigned pos = atomicAdd(counter, 1u);
        if (pos < NPIX) list[pos] = p;
    }
}

// ---------------- recheck: exact fp32 argmin for flagged pixels --------------
// item = (flagged pixel, 512-code chunk). Coalesced: 4 codes x 16 lanes per
// b128 (contiguous 1KB from L2-resident e_norm); intra-16-lane shfl reduce.
__global__ __launch_bounds__(256) void k_recheck(const float* __restrict__ zn,
                                                 const float* __restrict__ e_norm,
                                                 const float* __restrict__ se_half,
                                                 const unsigned* __restrict__ list,
                                                 const unsigned* __restrict__ counter,
                                                 unsigned long long* __restrict__ packed) {
    const int lane  = threadIdx.x & 63;
    const int k     = lane >> 4;        // code-in-group 0..3
    const int m     = lane & 15;        // c4 index 0..15
    const int wglob = (blockIdx.x * 256 + threadIdx.x) >> 6;
    const int nwav  = (gridDim.x * 256) >> 6;
    int cnt = (int)*counter; if (cnt > NPIX) cnt = NPIX;
    const int nitems = cnt * 16;
    const float4* e4 = (const float4*)e_norm;

    for (int item = wglob; item < nitems; item += nwav) {
        const int p     = (int)list[item >> 4];
        const int chunk = item & 15;
        const float4 zv = *(const float4*)(zn + p * EDIM + m * 4);  // bcast/16 lanes
        float best = 3.0e38f; int bidx = 0;
        #pragma unroll 2
        for (int t = 0; t < 128; ++t) {                // 4 codes per iteration
            const int n = chunk * 512 + t * 4 + k;     // lane's code this iter
            const float4 ev = e4[n * 16 + m];          // lane-linear: 1KB contiguous
            float s = fmaf(zv.w, ev.w, fmaf(zv.z, ev.z,
                      fmaf(zv.y, ev.y, zv.x * ev.x)));
            s += __shfl_xor(s, 1, 64); s += __shfl_xor(s, 2, 64);
            s += __shfl_xor(s, 4, 64); s += __shfl_xor(s, 8, 64);
            const float d = se_half[n] - s;            // all 16 lanes same d
            if (d < best) { best = d; bidx = n; }      // lane's codes ascending
        }
        #pragma unroll
        for (int mm = 1; mm <= 32; mm <<= 1) {         // wave first-min
            const float ob = __shfl_xor(best, mm, 64);
            const int   oi = __shfl_xor(bidx, mm, 64);
            if (ob < best || (ob == best && oi < bidx)) { best = ob; bidx = oi; }
        }
        if (lane == 0) {
            const unsigned long long key =
                ((unsigned long long)order_u32(best) << 32) | (unsigned)bidx;
            atomicMin(&packed[p], key);
        }
    }
}

// ---------------- finalize: write indices + gather z_q (4 thr/pixel) ---------
__global__ __launch_bounds__(256) void k_finalize(const unsigned* __restrict__ idx_arr,
                                                  const unsigned long long* __restrict__ packed,
                                                  const float* __restrict__ e_norm,
                                                  float* __restrict__ out) {
    const int pl = threadIdx.x & 63;
    const int q  = threadIdx.x >> 6;                  // channel quarter 0..3
    const int p  = blockIdx.x * 64 + pl;
    const unsigned v = idx_arr[p];
    const int bidx = (v & 0x80000000u) ? (int)(packed[p] & 0xFFFFFFFFull)
                                       : (int)v;
    if (q == 0) out[NPIX * EDIM + p] = (float)bidx;
    const int b = p >> 12, hw = p & (HW - 1);
    float* op = out + b * (EDIM * HW) + hw;
    const float4* ep4 = (const float4*)(e_norm + bidx * EDIM + q * 16);
    #pragma unroll
    for (int j = 0; j < 4; ++j) {
        const float4 e = ep4[j];
        const int c = q * 16 + j * 4;
        op[(c + 0) * HW] = e.x; op[(c + 1) * HW] = e.y;   // coalesced per c
        op[(c + 2) * HW] = e.z; op[(c + 3) * HW] = e.w;
    }
}

extern "C" void kernel_launch(void* const* d_in, const int* in_sizes, int n_in,
                              void* d_out, int out_size, void* d_ws, size_t ws_size,
                              hipStream_t stream) {
    const float* z   = (const float*)d_in[0];
    const float* emb = (const float*)d_in[1];
    float* out = (float*)d_out;

    // workspace layout (~14.6 MB)
    float* e_norm  = (float*)d_ws;                       // 2 MB
    float* se_half = e_norm + NE * EDIM;                 // 32 KB
    short* esw = (short*)(se_half + NE);                 // 1 MB (swizzled fp16)
    float* zn = (float*)(esw + NE * EDIM);               // 8 MB
    unsigned* idx_arr = (unsigned*)(zn + NPIX * EDIM);   // 128 KB
    unsigned* list    = idx_arr + NPIX;                  // 128 KB
    unsigned* counter = list + NPIX;                     // 4 B (+pad)
    unsigned long long* packed = (unsigned long long*)(counter + 64); // 256 KB
    float2*   pv = (float2*)(packed + NPIX);             // 2 MB
    unsigned* pi = (unsigned*)(pv + KSPLIT * NPIX);      // 1 MB

    k_prep<<<NE / 4 + NPIX / 256, 256, 0, stream>>>(emb, z, e_norm, se_half,
                                                    esw, zn, counter);
    k_mfma<<<dim3(NPIX / 128, KSPLIT), 256, 0, stream>>>(zn, esw, se_half, pv, pi);
    k_merge<<<NPIX / 256, 256, 0, stream>>>(pv, pi, idx_arr, list, counter, packed);
    k_recheck<<<1024, 256, 0, stream>>>(zn, e_norm, se_half, list, counter, packed);
    k_finalize<<<NPIX / 64, 256, 0, stream>>>(idx_arr, packed, e_norm, out);
}

// Round 3
// 225.460 us; speedup vs baseline: 1.0324x; 1.0324x over previous
//
#include <hip/hip_runtime.h>

// VectorQuantizer: z [8,64,64,64] fp32 (BCHW), embedding [8192,64] fp32.
// Outputs (concat): z_q [8,64,64,64] fp32 (BCHW), indices [32768] as fp32.
//
// R16: halve LDS traffic + kill the per-stage global-load serializer.
// R15 post-mortem: k_mfma is schedule/LDS-bound (floor ~20us LDS vs 88.6us
// measured; VALUBusy 68% >> MfmaUtil 16%). Levers:
//  (a) 64 pixels/wave (4 row-sets): same MFMA+selection totals, half the
//      waves -> half the LDS B-fragment re-reads (~10us floor), 2x compute
//      per barrier interval.
//  (b) z and e are both unit vectors -> 0.5|e|^2 == 0.5 (+-1e-7), so the
//      per-stage se_half loads are gone; C seeds with literal 2.0:
//      v = 2 + dot in [1,3] > 0 (mantissa-id trick intact). se_half still
//      used by k_recheck (exact fp32) so reference tie semantics unchanged.
// Selection (R14): 6-bit candidate id stuffed in low mantissa bits
// (v_and_or_b32), top-2 via med3+max (3 ops/elem).
// Scoring (R15): single-product fp16, MARGIN 6e-4 (~8 sigma of fp16 noise)
// flags near-ties for exact fp32 recheck.
// Staging (R12): global_load_lds 16B registerless from pre-swizzled codebook,
// LDS double-buffer, 1 barrier/stage, 0 bank conflicts.

#define NPIX 32768
#define NE   8192
#define EDIM 64
#define HW   4096
#define NSTAGE 64           // codes per LDS stage (4 subtiles of 16)
#define KSPLIT 8
#define CPS  (NE / KSPLIT)  // 1024 codes per split
#define NSTG (CPS / NSTAGE) // 16 stages per block
#define MARGIN 6.0e-4f
#define PPW  64             // pixels per wave (4 row-sets of 16)
#define NSET 4

typedef _Float16 f16x8 __attribute__((ext_vector_type(8)));
typedef float f32x4  __attribute__((ext_vector_type(4)));

__device__ __forceinline__ short f2h_bits(float x) {
    _Float16 h = (_Float16)x;
    short s; __builtin_memcpy(&s, &h, 2); return s;
}
// map float to unsigned with same total order
__device__ __forceinline__ unsigned int order_u32(float f) {
    unsigned int s = __float_as_uint(f);
    return (s & 0x80000000u) ? ~s : (s | 0x80000000u);
}
// async global->LDS, 16B/lane; HW writes lane i at lds_base + i*16 (wave-uniform base)
__device__ __forceinline__ void gload_lds16(const void* g, void* l) {
    __builtin_amdgcn_global_load_lds(
        (const __attribute__((address_space(1))) void*)g,
        (__attribute__((address_space(3))) void*)l, 16, 0, 0);
}

// ---------------- prep (fused): codebook (swizzled fp16) + pixels ------------
// esw layout = exactly the k_mfma LDS stage image: per 64-code stage, 8 combos
// (sub[4] x {k0,k1}) x 1KB; within combo, MFMA-B fragment order: slot
// frag_lane = (o&3)*16 + code_col holds 8 channels (16B).
__global__ __launch_bounds__(256) void k_prep(const float* __restrict__ emb,
                                              const float* __restrict__ z,
                                              float* __restrict__ e_norm,
                                              float* __restrict__ se_half,
                                              short* __restrict__ esw,
                                              float* __restrict__ zn,
                                              unsigned* __restrict__ counter) {
    if (blockIdx.x == 0 && threadIdx.x == 0) *counter = 0u;
    if (blockIdx.x < NE / 4) {
        // --- codebook: 1 code per wave, lane = channel ---
        const int wave = threadIdx.x >> 6;
        const int lane = threadIdx.x & 63;
        const int n = blockIdx.x * 4 + wave;
        float v = emb[n * EDIM + lane];
        float ss = v * v;
        #pragma unroll
        for (int off = 32; off; off >>= 1) ss += __shfl_xor(ss, off, 64);
        const float inv = 1.0f / fmaxf(sqrtf(ss), 1e-12f);
        const float en = v * inv;
        e_norm[n * EDIM + lane] = en;
        // swizzled fp16 write (c = lane)
        const int stage = n >> 6, cs = n & 63;
        const int sub = cs >> 4, colb = cs & 15;
        const int o = lane >> 3, j = lane & 7;     // o: khalf=o>>2, quad=o&3
        const int slot = ((o & 3) * 16 + colb) * 8 + j;
        short* sbase = esw + stage * 4096 + (sub * 2 + (o >> 2)) * 512;
        sbase[slot] = f2h_bits(en);
        float s2 = en * en;
        #pragma unroll
        for (int off = 32; off; off >>= 1) s2 += __shfl_xor(s2, off, 64);
        if (lane == 0) se_half[n] = 0.5f * s2;
    } else {
        // --- pixels: normalize -> zn fp32 row-major [p][c] ---
        const int p = (blockIdx.x - NE / 4) * 256 + threadIdx.x;
        const int b = p >> 12, hw = p & (HW - 1);
        const float* zp = z + b * (EDIM * HW) + hw;
        float ss = 0.0f;
        for (int c = 0; c < EDIM; ++c) { const float v = zp[c * HW]; ss = fmaf(v, v, ss); }
        const float inv = 1.0f / fmaxf(sqrtf(ss), 1e-12f);
        for (int c4 = 0; c4 < 16; ++c4) {
            float4 o;
            o.x = zp[(c4 * 4 + 0) * HW] * inv;
            o.y = zp[(c4 * 4 + 1) * HW] * inv;
            o.z = zp[(c4 * 4 + 2) * HW] * inv;
            o.w = zp[(c4 * 4 + 3) * HW] * inv;
            *(float4*)(zn + p * EDIM + c4 * 4) = o;
        }
    }
}

// ---------------- k_mfma: split-K partial top-2 per pixel (max-space) --------
// Block: 4 waves x 64 pixels = 256 pixels, one codebook eighth (blockIdx.y).
// v = acc[r] = dot + 2 in [1,3]; argmin dist == argmax v (unit vectors).
// Low 6 mantissa bits carry the candidate id (stage*4+sub); near-ties
// (< MARGIN, covers fp16 rounding at ~8 sigma) are flagged and resolved
// exactly in k_recheck. Layouts (HW-verified): A[m=lane&15][k=quad*8+j],
// B[k=quad*8+j][n=lane&15], C/D row=(lane>>4)*4+reg, col=lane&15.
__global__ __launch_bounds__(256, 1) void k_mfma(const float* __restrict__ zn,
                                                 const short* __restrict__ esw,
                                                 float2* __restrict__ pv,   // [g][p] {b1,b2} (max-space)
                                                 unsigned* __restrict__ pi) // [g][p] i1
{
    __shared__ __align__(16) short es[2][NSTAGE * EDIM];   // 2 x 8KB

    const int tid  = threadIdx.x;             // 0..255
    const int wave = tid >> 6, lane = tid & 63;
    const int quad = lane >> 4, col = lane & 15;
    const int p0   = blockIdx.x * (4 * PPW) + wave * PPW;  // wave's 64 pixels
    const int g    = blockIdx.y;                           // codebook eighth
    const int kbase = g * CPS;

    // A fragments: 4 sets of 16 pixels; fp32 zn -> fp16 (single product)
    f16x8 ah[NSET][2];
    #pragma unroll
    for (int s = 0; s < NSET; ++s) {
        const float* zr = zn + (p0 + s * 16 + col) * EDIM;
        #pragma unroll
        for (int kc = 0; kc < 2; ++kc) {
            float f[8];
            *(float4*)(f + 0) = *(const float4*)(zr + kc * 32 + quad * 8 + 0);
            *(float4*)(f + 4) = *(const float4*)(zr + kc * 32 + quad * 8 + 4);
            #pragma unroll
            for (int i = 0; i < 8; ++i) ah[s][kc][i] = (_Float16)f[i];
        }
    }

    // top-2 state in max-space; values stuffed with 6-bit id; b1 >= b2 invariant
    float b1[NSET][4], b2[NSET][4];
    #pragma unroll
    for (int s = 0; s < NSET; ++s)
        #pragma unroll
        for (int r = 0; r < 4; ++r) { b1[s][r] = 0.0f; b2[s][r] = 0.0f; }

    const f32x4 cini = {2.0f, 2.0f, 2.0f, 2.0f};   // |z|=|e|=1 -> bias constant

    // this wave's staging window: src and dst are both uniform + lane*16
    const int combo0 = wave * 2;
    const char* gsrc0 = (const char*)esw + (size_t)kbase * 128
                        + combo0 * 1024 + lane * 16;
    // prologue: issue stage 0 -> buf 0
    #pragma unroll
    for (int it = 0; it < 2; ++it)
        gload_lds16(gsrc0 + it * 1024, (char*)&es[0][0] + (combo0 + it) * 1024);

    for (int nb = 0; nb < NSTG; ++nb) {
        const int cur = nb & 1;
        __syncthreads();   // vmcnt drained: buf[cur] complete; buf[cur^1] reusable
        if (nb + 1 < NSTG) {
            const char* gsrc = gsrc0 + (size_t)(nb + 1) * (NSTAGE * EDIM * 2);
            #pragma unroll
            for (int it = 0; it < 2; ++it)
                gload_lds16(gsrc + it * 1024,
                            (char*)&es[cur ^ 1][0] + (combo0 + it) * 1024);
        }

        const short* esb = es[cur];
        #pragma unroll
        for (int sub = 0; sub < 4; ++sub) {
            const short* base = esb + sub * 1024;
            const f16x8 bh0 = *(const f16x8*)(base + lane * 8);
            const f16x8 bh1 = *(const f16x8*)(base + 512 + lane * 8);
            const unsigned sid = (unsigned)((nb << 2) | sub);  // 6-bit id, uniform
            #pragma unroll
            for (int s = 0; s < NSET; ++s) {
                // 2-deep chain seeded with C = {2.0}
                f32x4 acc;
                acc = __builtin_amdgcn_mfma_f32_16x16x32_f16(ah[s][0], bh0, cini, 0, 0, 0);
                acc = __builtin_amdgcn_mfma_f32_16x16x32_f16(ah[s][1], bh1, acc, 0, 0, 0);
                #pragma unroll
                for (int r = 0; r < 4; ++r) {
                    // stuff candidate id into low mantissa bits (v_and_or_b32)
                    const float v = __uint_as_float(
                        (__float_as_uint(acc[r]) & 0xFFFFFFC0u) | sid);
                    // b1>=b2 invariant -> med3 == new 2nd-max; then running max
                    b2[s][r] = __builtin_amdgcn_fmed3f(v, b2[s][r], b1[s][r]);
                    b1[s][r] = fmaxf(b1[s][r], v);
                }
            }
        }
    }

    // recover winning index from b1's stuffed id (col is lane-implicit)
    int i1[NSET][4];
    #pragma unroll
    for (int s = 0; s < NSET; ++s)
        #pragma unroll
        for (int r = 0; r < 4; ++r) {
            const unsigned id6 = __float_as_uint(b1[s][r]) & 63u;
            i1[s][r] = kbase + (int)(id6 << 4) + col;
        }

    // merge top-2 across the 16 col-lanes (xor 1,2,4,8 stays inside quad group)
    #pragma unroll
    for (int m = 1; m <= 8; m <<= 1) {
        #pragma unroll
        for (int s = 0; s < NSET; ++s)
            #pragma unroll
            for (int r = 0; r < 4; ++r) {
                const float ob1 = __shfl_xor(b1[s][r], m, 64);
                const int   oi1 = __shfl_xor(i1[s][r], m, 64);
                const float ob2 = __shfl_xor(b2[s][r], m, 64);
                const bool take = (ob1 > b1[s][r]) || (ob1 == b1[s][r] && oi1 < i1[s][r]);
                b2[s][r] = fmaxf(fmaxf(b2[s][r], ob2), fminf(b1[s][r], ob1));
                b1[s][r] = take ? ob1 : b1[s][r];
                i1[s][r] = take ? oi1 : i1[s][r];
            }
    }
    if (col == 0) {
        #pragma unroll
        for (int s = 0; s < NSET; ++s)
            #pragma unroll
            for (int r = 0; r < 4; ++r) {
                const int p = p0 + s * 16 + quad * 4 + r;   // C/D row = quad*4 + r
                pv[g * NPIX + p] = make_float2(b1[s][r], b2[s][r]);
                pi[g * NPIX + p] = (unsigned)i1[s][r];
            }
    }
}

// ---------------- merge: combine KSPLIT partials (max-space), flag -----------
__global__ __launch_bounds__(256) void k_merge(const float2* __restrict__ pv,
                                               const unsigned* __restrict__ pi,
                                               unsigned* __restrict__ idx_arr,
                                               unsigned* __restrict__ list,
                                               unsigned* __restrict__ counter,
                                               unsigned long long* __restrict__ packed) {
    const int p = blockIdx.x * 256 + threadIdx.x;
    float2 v[KSPLIT]; unsigned ix[KSPLIT];
    #pragma unroll
    for (int gg = 0; gg < KSPLIT; ++gg) { v[gg] = pv[gg * NPIX + p]; ix[gg] = pi[gg * NPIX + p]; }
    // ascending group order + strict > == np first-occurrence tie semantics
    float b1 = v[0].x; unsigned i1 = ix[0]; int win = 0;
    #pragma unroll
    for (int gg = 1; gg < KSPLIT; ++gg)
        if (v[gg].x > b1) { b1 = v[gg].x; i1 = ix[gg]; win = gg; }
    float b2 = -3.0e38f;
    #pragma unroll
    for (int gg = 0; gg < KSPLIT; ++gg) {
        b2 = fmaxf(b2, v[gg].y);
        if (gg != win) b2 = fmaxf(b2, v[gg].x);
    }
    const bool fl = (b1 - b2 < MARGIN);   // gap in v-space == gap in dist/2
    idx_arr[p] = i1 | (fl ? 0x80000000u : 0u);
    if (fl) {
        packed[p] = ~0ull;
        const unsigned pos = atomicAdd(counter, 1u);
        if (pos < NPIX) list[pos] = p;
    }
}

// ---------------- recheck: exact fp32 argmin for flagged pixels --------------
// item = (flagged pixel, 512-code chunk). Coalesced: 4 codes x 16 lanes per
// b128 (contiguous 1KB from L2-resident e_norm); intra-16-lane shfl reduce.
__global__ __launch_bounds__(256) void k_recheck(const float* __restrict__ zn,
                                                 const float* __restrict__ e_norm,
                                                 const float* __restrict__ se_half,
                                                 const unsigned* __restrict__ list,
                                                 const unsigned* __restrict__ counter,
                                                 unsigned long long* __restrict__ packed) {
    const int lane  = threadIdx.x & 63;
    const int k     = lane >> 4;        // code-in-group 0..3
    const int m     = lane & 15;        // c4 index 0..15
    const int wglob = (blockIdx.x * 256 + threadIdx.x) >> 6;
    const int nwav  = (gridDim.x * 256) >> 6;
    int cnt = (int)*counter; if (cnt > NPIX) cnt = NPIX;
    const int nitems = cnt * 16;
    const float4* e4 = (const float4*)e_norm;

    for (int item = wglob; item < nitems; item += nwav) {
        const int p     = (int)list[item >> 4];
        const int chunk = item & 15;
        const float4 zv = *(const float4*)(zn + p * EDIM + m * 4);  // bcast/16 lanes
        float best = 3.0e38f; int bidx = 0;
        #pragma unroll 2
        for (int t = 0; t < 128; ++t) {                // 4 codes per iteration
            const int n = chunk * 512 + t * 4 + k;     // lane's code this iter
            const float4 ev = e4[n * 16 + m];          // lane-linear: 1KB contiguous
            float s = fmaf(zv.w, ev.w, fmaf(zv.z, ev.z,
                      fmaf(zv.y, ev.y, zv.x * ev.x)));
            s += __shfl_xor(s, 1, 64); s += __shfl_xor(s, 2, 64);
            s += __shfl_xor(s, 4, 64); s += __shfl_xor(s, 8, 64);
            const float d = se_half[n] - s;            // all 16 lanes same d
            if (d < best) { best = d; bidx = n; }      // lane's codes ascending
        }
        #pragma unroll
        for (int mm = 1; mm <= 32; mm <<= 1) {         // wave first-min
            const float ob = __shfl_xor(best, mm, 64);
            const int   oi = __shfl_xor(bidx, mm, 64);
            if (ob < best || (ob == best && oi < bidx)) { best = ob; bidx = oi; }
        }
        if (lane == 0) {
            const unsigned long long key =
                ((unsigned long long)order_u32(best) << 32) | (unsigned)bidx;
            atomicMin(&packed[p], key);
        }
    }
}

// ---------------- finalize: write indices + gather z_q (4 thr/pixel) ---------
__global__ __launch_bounds__(256) void k_finalize(const unsigned* __restrict__ idx_arr,
                                                  const unsigned long long* __restrict__ packed,
                                                  const float* __restrict__ e_norm,
                                                  float* __restrict__ out) {
    const int pl = threadIdx.x & 63;
    const int q  = threadIdx.x >> 6;                  // channel quarter 0..3
    const int p  = blockIdx.x * 64 + pl;
    const unsigned v = idx_arr[p];
    const int bidx = (v & 0x80000000u) ? (int)(packed[p] & 0xFFFFFFFFull)
                                       : (int)v;
    if (q == 0) out[NPIX * EDIM + p] = (float)bidx;
    const int b = p >> 12, hw = p & (HW - 1);
    float* op = out + b * (EDIM * HW) + hw;
    const float4* ep4 = (const float4*)(e_norm + bidx * EDIM + q * 16);
    #pragma unroll
    for (int j = 0; j < 4; ++j) {
        const float4 e = ep4[j];
        const int c = q * 16 + j * 4;
        op[(c + 0) * HW] = e.x; op[(c + 1) * HW] = e.y;   // coalesced per c
        op[(c + 2) * HW] = e.z; op[(c + 3) * HW] = e.w;
    }
}

extern "C" void kernel_launch(void* const* d_in, const int* in_sizes, int n_in,
                              void* d_out, int out_size, void* d_ws, size_t ws_size,
                              hipStream_t stream) {
    const float* z   = (const float*)d_in[0];
    const float* emb = (const float*)d_in[1];
    float* out = (float*)d_out;

    // workspace layout (~14.6 MB)
    float* e_norm  = (float*)d_ws;                       // 2 MB
    float* se_half = e_norm + NE * EDIM;                 // 32 KB
    short* esw = (short*)(se_half + NE);                 // 1 MB (swizzled fp16)
    float* zn = (float*)(esw + NE * EDIM);               // 8 MB
    unsigned* idx_arr = (unsigned*)(zn + NPIX * EDIM);   // 128 KB
    unsigned* list    = idx_arr + NPIX;                  // 128 KB
    unsigned* counter = list + NPIX;                     // 4 B (+pad)
    unsigned long long* packed = (unsigned long long*)(counter + 64); // 256 KB
    float2*   pv = (float2*)(packed + NPIX);             // 2 MB
    unsigned* pi = (unsigned*)(pv + KSPLIT * NPIX);      // 1 MB

    k_prep<<<NE / 4 + NPIX / 256, 256, 0, stream>>>(emb, z, e_norm, se_half,
                                                    esw, zn, counter);
    k_mfma<<<dim3(NPIX / 256, KSPLIT), 256, 0, stream>>>(zn, esw, pv, pi);
    k_merge<<<NPIX / 256, 256, 0, stream>>>(pv, pi, idx_arr, list, counter, packed);
    k_recheck<<<1024, 256, 0, stream>>>(zn, e_norm, se_half, list, counter, packed);
    k_finalize<<<NPIX / 64, 256, 0, stream>>>(idx_arr, packed, e_norm, out);
}

// Round 4
// 210.492 us; speedup vs baseline: 1.1059x; 1.0711x over previous
//
#include <hip/hip_runtime.h>

// VectorQuantizer: z [8,64,64,64] fp32 (BCHW), embedding [8192,64] fp32.
// Outputs (concat): z_q [8,64,64,64] fp32 (BCHW), indices [32768] as fp32.
//
// R17: epoch/latency attack (instruction diets R14-R16 were nulls).
//  (a) k_mfma: PPW=32 (R15 point), NSTAGE 64->128: barrier epochs per block
//      16->8, 2x compute per epoch (DMA slack + fixed-cost amortization).
//      LDS 2x16KB. Grid 2048 blocks (8/CU queued, ~5 resident by LDS).
//  (b) k_recheck: 4 independent shfl-reduce chains interleaved (was one
//      4-deep dependent chain per 4 codes -> ~150 cyc serial x 128 iters).
//      Grid 2048 blocks.
//  (c) k_prep: single-pass pixel normalize (64 regs) - halves z traffic.
// Selection (R14): 6-bit candidate id stuffed in low mantissa bits,
// top-2 via med3+max (3 ops/elem). v = 2 + dot in [1,3] > 0 (unit vectors).
// Scoring (R15): single-product fp16, MARGIN 6e-4 flags near-ties for exact
// fp32 recheck (reference tie semantics preserved).
// Staging (R12): global_load_lds 16B registerless from pre-swizzled codebook,
// LDS double-buffer, 1 barrier/stage, 0 bank conflicts.

#define NPIX 32768
#define NE   8192
#define EDIM 64
#define HW   4096
#define NSTAGE 128          // codes per LDS stage (8 subtiles of 16)
#define KSPLIT 8
#define CPS  (NE / KSPLIT)  // 1024 codes per split
#define NSTG (CPS / NSTAGE) // 8 stages per block
#define MARGIN 6.0e-4f
#define NSET 2              // row-sets of 16 pixels per wave (PPW=32)

typedef _Float16 f16x8 __attribute__((ext_vector_type(8)));
typedef float f32x4  __attribute__((ext_vector_type(4)));

__device__ __forceinline__ short f2h_bits(float x) {
    _Float16 h = (_Float16)x;
    short s; __builtin_memcpy(&s, &h, 2); return s;
}
// map float to unsigned with same total order
__device__ __forceinline__ unsigned int order_u32(float f) {
    unsigned int s = __float_as_uint(f);
    return (s & 0x80000000u) ? ~s : (s | 0x80000000u);
}
// async global->LDS, 16B/lane; HW writes lane i at lds_base + i*16 (wave-uniform base)
__device__ __forceinline__ void gload_lds16(const void* g, void* l) {
    __builtin_amdgcn_global_load_lds(
        (const __attribute__((address_space(1))) void*)g,
        (__attribute__((address_space(3))) void*)l, 16, 0, 0);
}

// ---------------- prep (fused): codebook (swizzled fp16) + pixels ------------
// esw layout = exactly the k_mfma LDS stage image: per 64-code group, 8 combos
// (sub[4] x {k0,k1}) x 1KB; within combo, MFMA-B fragment order: slot
// frag_lane = (o&3)*16 + code_col holds 8 channels (16B). NSTAGE=128 stages
// are just two consecutive 64-code groups (contiguous 16KB).
__global__ __launch_bounds__(256) void k_prep(const float* __restrict__ emb,
                                              const float* __restrict__ z,
                                              float* __restrict__ e_norm,
                                              float* __restrict__ se_half,
                                              short* __restrict__ esw,
                                              float* __restrict__ zn,
                                              unsigned* __restrict__ counter) {
    if (blockIdx.x == 0 && threadIdx.x == 0) *counter = 0u;
    if (blockIdx.x < NE / 4) {
        // --- codebook: 1 code per wave, lane = channel ---
        const int wave = threadIdx.x >> 6;
        const int lane = threadIdx.x & 63;
        const int n = blockIdx.x * 4 + wave;
        float v = emb[n * EDIM + lane];
        float ss = v * v;
        #pragma unroll
        for (int off = 32; off; off >>= 1) ss += __shfl_xor(ss, off, 64);
        const float inv = 1.0f / fmaxf(sqrtf(ss), 1e-12f);
        const float en = v * inv;
        e_norm[n * EDIM + lane] = en;
        // swizzled fp16 write (c = lane)
        const int stage = n >> 6, cs = n & 63;
        const int sub = cs >> 4, colb = cs & 15;
        const int o = lane >> 3, j = lane & 7;     // o: khalf=o>>2, quad=o&3
        const int slot = ((o & 3) * 16 + colb) * 8 + j;
        short* sbase = esw + stage * 4096 + (sub * 2 + (o >> 2)) * 512;
        sbase[slot] = f2h_bits(en);
        float s2 = en * en;
        #pragma unroll
        for (int off = 32; off; off >>= 1) s2 += __shfl_xor(s2, off, 64);
        if (lane == 0) se_half[n] = 0.5f * s2;
    } else {
        // --- pixels: single-pass normalize -> zn fp32 row-major [p][c] ---
        const int p = (blockIdx.x - NE / 4) * 256 + threadIdx.x;
        const int b = p >> 12, hw = p & (HW - 1);
        const float* zp = z + b * (EDIM * HW) + hw;
        float v[EDIM];
        #pragma unroll
        for (int c = 0; c < EDIM; ++c) v[c] = zp[c * HW];
        float ss = 0.0f;
        #pragma unroll
        for (int c = 0; c < EDIM; ++c) ss = fmaf(v[c], v[c], ss);
        const float inv = 1.0f / fmaxf(sqrtf(ss), 1e-12f);
        #pragma unroll
        for (int c4 = 0; c4 < 16; ++c4) {
            float4 o;
            o.x = v[c4 * 4 + 0] * inv;
            o.y = v[c4 * 4 + 1] * inv;
            o.z = v[c4 * 4 + 2] * inv;
            o.w = v[c4 * 4 + 3] * inv;
            *(float4*)(zn + p * EDIM + c4 * 4) = o;
        }
    }
}

// ---------------- k_mfma: split-K partial top-2 per pixel (max-space) --------
// Block: 4 waves x 32 pixels = 128 pixels, one codebook eighth (blockIdx.y).
// v = acc[r] = dot + 2 in [1,3]; argmin dist == argmax v (unit vectors).
// Low 6 mantissa bits carry the candidate id (stage*8+sub); near-ties
// (< MARGIN, covers fp16 rounding) are flagged and resolved exactly in
// k_recheck. Layouts (HW-verified): A[m=lane&15][k=quad*8+j],
// B[k=quad*8+j][n=lane&15], C/D row=(lane>>4)*4+reg, col=lane&15.
__global__ __launch_bounds__(256, 1) void k_mfma(const float* __restrict__ zn,
                                                 const short* __restrict__ esw,
                                                 float2* __restrict__ pv,   // [g][p] {b1,b2} (max-space)
                                                 unsigned* __restrict__ pi) // [g][p] i1
{
    __shared__ __align__(16) short es[2][NSTAGE * EDIM];   // 2 x 16KB

    const int tid  = threadIdx.x;             // 0..255
    const int wave = tid >> 6, lane = tid & 63;
    const int quad = lane >> 4, col = lane & 15;
    const int p0   = blockIdx.x * 128 + wave * 32;  // wave's 32 pixels (2 sets)
    const int g    = blockIdx.y;                    // codebook eighth
    const int kbase = g * CPS;

    // A fragments: 2 sets of 16 pixels; fp32 zn -> fp16 (single product)
    f16x8 ah[NSET][2];
    #pragma unroll
    for (int s = 0; s < NSET; ++s) {
        const float* zr = zn + (p0 + s * 16 + col) * EDIM;
        #pragma unroll
        for (int kc = 0; kc < 2; ++kc) {
            float f[8];
            *(float4*)(f + 0) = *(const float4*)(zr + kc * 32 + quad * 8 + 0);
            *(float4*)(f + 4) = *(const float4*)(zr + kc * 32 + quad * 8 + 4);
            #pragma unroll
            for (int i = 0; i < 8; ++i) ah[s][kc][i] = (_Float16)f[i];
        }
    }

    // top-2 state in max-space; values stuffed with 6-bit id; b1 >= b2 invariant
    float b1[NSET][4], b2[NSET][4];
    #pragma unroll
    for (int s = 0; s < NSET; ++s)
        #pragma unroll
        for (int r = 0; r < 4; ++r) { b1[s][r] = 0.0f; b2[s][r] = 0.0f; }

    const f32x4 cini = {2.0f, 2.0f, 2.0f, 2.0f};   // |z|=|e|=1 -> bias constant

    // this wave's staging window: src and dst are both uniform + lane*16
    const int combo0 = wave * 4;   // 16 combos x 1KB per 16KB stage
    const char* gsrc0 = (const char*)esw + (size_t)kbase * 128
                        + combo0 * 1024 + lane * 16;
    // prologue: issue stage 0 -> buf 0
    #pragma unroll
    for (int it = 0; it < 4; ++it)
        gload_lds16(gsrc0 + it * 1024, (char*)&es[0][0] + (combo0 + it) * 1024);

    for (int nb = 0; nb < NSTG; ++nb) {
        const int cur = nb & 1;
        __syncthreads();   // vmcnt drained: buf[cur] complete; buf[cur^1] reusable
        if (nb + 1 < NSTG) {
            const char* gsrc = gsrc0 + (size_t)(nb + 1) * (NSTAGE * EDIM * 2);
            #pragma unroll
            for (int it = 0; it < 4; ++it)
                gload_lds16(gsrc + it * 1024,
                            (char*)&es[cur ^ 1][0] + (combo0 + it) * 1024);
        }

        const short* esb = es[cur];
        #pragma unroll
        for (int sub = 0; sub < 8; ++sub) {       // 8 subtiles of 16 codes
            const short* base = esb + sub * 1024;
            const f16x8 bh0 = *(const f16x8*)(base + lane * 8);
            const f16x8 bh1 = *(const f16x8*)(base + 512 + lane * 8);
            const unsigned sid = (unsigned)((nb << 3) | sub);  // 6-bit id, uniform
            #pragma unroll
            for (int s = 0; s < NSET; ++s) {
                // 2-deep chain seeded with C = {2.0}
                f32x4 acc;
                acc = __builtin_amdgcn_mfma_f32_16x16x32_f16(ah[s][0], bh0, cini, 0, 0, 0);
                acc = __builtin_amdgcn_mfma_f32_16x16x32_f16(ah[s][1], bh1, acc, 0, 0, 0);
                #pragma unroll
                for (int r = 0; r < 4; ++r) {
                    // stuff candidate id into low mantissa bits (v_and_or_b32)
                    const float v = __uint_as_float(
                        (__float_as_uint(acc[r]) & 0xFFFFFFC0u) | sid);
                    // b1>=b2 invariant -> med3 == new 2nd-max; then running max
                    b2[s][r] = __builtin_amdgcn_fmed3f(v, b2[s][r], b1[s][r]);
                    b1[s][r] = fmaxf(b1[s][r], v);
                }
            }
        }
    }

    // recover winning index from b1's stuffed id (col is lane-implicit)
    int i1[NSET][4];
    #pragma unroll
    for (int s = 0; s < NSET; ++s)
        #pragma unroll
        for (int r = 0; r < 4; ++r) {
            const unsigned id6 = __float_as_uint(b1[s][r]) & 63u;
            i1[s][r] = kbase + (int)(id6 << 4) + col;
        }

    // merge top-2 across the 16 col-lanes (xor 1,2,4,8 stays inside quad group)
    #pragma unroll
    for (int m = 1; m <= 8; m <<= 1) {
        #pragma unroll
        for (int s = 0; s < NSET; ++s)
            #pragma unroll
            for (int r = 0; r < 4; ++r) {
                const float ob1 = __shfl_xor(b1[s][r], m, 64);
                const int   oi1 = __shfl_xor(i1[s][r], m, 64);
                const float ob2 = __shfl_xor(b2[s][r], m, 64);
                const bool take = (ob1 > b1[s][r]) || (ob1 == b1[s][r] && oi1 < i1[s][r]);
                b2[s][r] = fmaxf(fmaxf(b2[s][r], ob2), fminf(b1[s][r], ob1));
                b1[s][r] = take ? ob1 : b1[s][r];
                i1[s][r] = take ? oi1 : i1[s][r];
            }
    }
    if (col == 0) {
        #pragma unroll
        for (int s = 0; s < NSET; ++s)
            #pragma unroll
            for (int r = 0; r < 4; ++r) {
                const int p = p0 + s * 16 + quad * 4 + r;   // C/D row = quad*4 + r
                pv[g * NPIX + p] = make_float2(b1[s][r], b2[s][r]);
                pi[g * NPIX + p] = (unsigned)i1[s][r];
            }
    }
}

// ---------------- merge: combine KSPLIT partials (max-space), flag -----------
__global__ __launch_bounds__(256) void k_merge(const float2* __restrict__ pv,
                                               const unsigned* __restrict__ pi,
                                               unsigned* __restrict__ idx_arr,
                                               unsigned* __restrict__ list,
                                               unsigned* __restrict__ counter,
                                               unsigned long long* __restrict__ packed) {
    const int p = blockIdx.x * 256 + threadIdx.x;
    float2 v[KSPLIT]; unsigned ix[KSPLIT];
    #pragma unroll
    for (int gg = 0; gg < KSPLIT; ++gg) { v[gg] = pv[gg * NPIX + p]; ix[gg] = pi[gg * NPIX + p]; }
    // ascending group order + strict > == np first-occurrence tie semantics
    float b1 = v[0].x; unsigned i1 = ix[0]; int win = 0;
    #pragma unroll
    for (int gg = 1; gg < KSPLIT; ++gg)
        if (v[gg].x > b1) { b1 = v[gg].x; i1 = ix[gg]; win = gg; }
    float b2 = -3.0e38f;
    #pragma unroll
    for (int gg = 0; gg < KSPLIT; ++gg) {
        b2 = fmaxf(b2, v[gg].y);
        if (gg != win) b2 = fmaxf(b2, v[gg].x);
    }
    const bool fl = (b1 - b2 < MARGIN);   // gap in v-space == gap in dist/2
    idx_arr[p] = i1 | (fl ? 0x80000000u : 0u);
    if (fl) {
        packed[p] = ~0ull;
        const unsigned pos = atomicAdd(counter, 1u);
        if (pos < NPIX) list[pos] = p;
    }
}

// ---------------- recheck: exact fp32 argmin for flagged pixels --------------
// item = (flagged pixel, 512-code chunk). Coalesced: 4 codes x 16 lanes per
// b128 (contiguous 1KB from L2-resident e_norm). 4 independent shfl-reduce
// chains per iteration (16 codes) - latency-hiding across chains.
__global__ __launch_bounds__(256) void k_recheck(const float* __restrict__ zn,
                                                 const float* __restrict__ e_norm,
                                                 const float* __restrict__ se_half,
                                                 const unsigned* __restrict__ list,
                                                 const unsigned* __restrict__ counter,
                                                 unsigned long long* __restrict__ packed) {
    const int lane  = threadIdx.x & 63;
    const int k     = lane >> 4;        // code-in-group 0..3
    const int m     = lane & 15;        // c4 index 0..15
    const int wglob = (blockIdx.x * 256 + threadIdx.x) >> 6;
    const int nwav  = (gridDim.x * 256) >> 6;
    int cnt = (int)*counter; if (cnt > NPIX) cnt = NPIX;
    const int nitems = cnt * 16;
    const float4* e4 = (const float4*)e_norm;

    for (int item = wglob; item < nitems; item += nwav) {
        const int p     = (int)list[item >> 4];
        const int chunk = item & 15;
        const float4 zv = *(const float4*)(zn + p * EDIM + m * 4);  // bcast/16 lanes
        float best = 3.0e38f; int bidx = 0;
        for (int t4 = 0; t4 < 32; ++t4) {              // 16 codes per iteration
            float s[4]; int n[4];
            #pragma unroll
            for (int j = 0; j < 4; ++j) {
                n[j] = chunk * 512 + (t4 * 4 + j) * 4 + k;
                const float4 ev = e4[n[j] * 16 + m];   // lane-linear: 1KB contiguous
                s[j] = fmaf(zv.w, ev.w, fmaf(zv.z, ev.z,
                       fmaf(zv.y, ev.y, zv.x * ev.x)));
            }
            // 4 independent reduce chains (compiler interleaves)
            #pragma unroll
            for (int j = 0; j < 4; ++j) s[j] += __shfl_xor(s[j], 1, 64);
            #pragma unroll
            for (int j = 0; j < 4; ++j) s[j] += __shfl_xor(s[j], 2, 64);
            #pragma unroll
            for (int j = 0; j < 4; ++j) s[j] += __shfl_xor(s[j], 4, 64);
            #pragma unroll
            for (int j = 0; j < 4; ++j) s[j] += __shfl_xor(s[j], 8, 64);
            #pragma unroll
            for (int j = 0; j < 4; ++j) {              // codes ascend over (t4,j)
                const float d = se_half[n[j]] - s[j];
                if (d < best) { best = d; bidx = n[j]; }
            }
        }
        #pragma unroll
        for (int mm = 1; mm <= 32; mm <<= 1) {         // wave first-min
            const float ob = __shfl_xor(best, mm, 64);
            const int   oi = __shfl_xor(bidx, mm, 64);
            if (ob < best || (ob == best && oi < bidx)) { best = ob; bidx = oi; }
        }
        if (lane == 0) {
            const unsigned long long key =
                ((unsigned long long)order_u32(best) << 32) | (unsigned)bidx;
            atomicMin(&packed[p], key);
        }
    }
}

// ---------------- finalize: write indices + gather z_q (4 thr/pixel) ---------
__global__ __launch_bounds__(256) void k_finalize(const unsigned* __restrict__ idx_arr,
                                                  const unsigned long long* __restrict__ packed,
                                                  const float* __restrict__ e_norm,
                                                  float* __restrict__ out) {
    const int pl = threadIdx.x & 63;
    const int q  = threadIdx.x >> 6;                  // channel quarter 0..3
    const int p  = blockIdx.x * 64 + pl;
    const unsigned v = idx_arr[p];
    const int bidx = (v & 0x80000000u) ? (int)(packed[p] & 0xFFFFFFFFull)
                                       : (int)v;
    if (q == 0) out[NPIX * EDIM + p] = (float)bidx;
    const int b = p >> 12, hw = p & (HW - 1);
    float* op = out + b * (EDIM * HW) + hw;
    const float4* ep4 = (const float4*)(e_norm + bidx * EDIM + q * 16);
    #pragma unroll
    for (int j = 0; j < 4; ++j) {
        const float4 e = ep4[j];
        const int c = q * 16 + j * 4;
        op[(c + 0) * HW] = e.x; op[(c + 1) * HW] = e.y;   // coalesced per c
        op[(c + 2) * HW] = e.z; op[(c + 3) * HW] = e.w;
    }
}

extern "C" void kernel_launch(void* const* d_in, const int* in_sizes, int n_in,
                              void* d_out, int out_size, void* d_ws, size_t ws_size,
                              hipStream_t stream) {
    const float* z   = (const float*)d_in[0];
    const float* emb = (const float*)d_in[1];
    float* out = (float*)d_out;

    // workspace layout (~14.6 MB)
    float* e_norm  = (float*)d_ws;                       // 2 MB
    float* se_half = e_norm + NE * EDIM;                 // 32 KB
    short* esw = (short*)(se_half + NE);                 // 1 MB (swizzled fp16)
    float* zn = (float*)(esw + NE * EDIM);               // 8 MB
    unsigned* idx_arr = (unsigned*)(zn + NPIX * EDIM);   // 128 KB
    unsigned* list    = idx_arr + NPIX;                  // 128 KB
    unsigned* counter = list + NPIX;                     // 4 B (+pad)
    unsigned long long* packed = (unsigned long long*)(counter + 64); // 256 KB
    float2*   pv = (float2*)(packed + NPIX);             // 2 MB
    unsigned* pi = (unsigned*)(pv + KSPLIT * NPIX);      // 1 MB

    k_prep<<<NE / 4 + NPIX / 256, 256, 0, stream>>>(emb, z, e_norm, se_half,
                                                    esw, zn, counter);
    k_mfma<<<dim3(NPIX / 128, KSPLIT), 256, 0, stream>>>(zn, esw, pv, pi);
    k_merge<<<NPIX / 256, 256, 0, stream>>>(pv, pi, idx_arr, list, counter, packed);
    k_recheck<<<2048, 256, 0, stream>>>(zn, e_norm, se_half, list, counter, packed);
    k_finalize<<<NPIX / 64, 256, 0, stream>>>(idx_arr, packed, e_norm, out);
}